// Round 6
// baseline (235.638 us; speedup 1.0000x reference)
//
#include <hip/hip_runtime.h>
#include <hip/hip_bf16.h>
#include <math.h>

// SAGAN self-attention, B=4, H=W=64, C=256, Ck=32, N=4096 (16384 total rows).
//   prep_wtf : WTf fragment-contiguous repack of [Wf|Wg|Wh]^T (bf16), coalesced writes.
//   proj_mfma: 16-row blocks, grid 1024, 4 symmetric waves (1 fg tile + 4 h tiles each)
//              -> f,g bf16 [B*N,32], hT bf16 [B,256,4096] (transposed via swapped MFMA).
//   attn     : flash attention, Q-tile 32, grid 512 (2 blocks/CU), 4 waves
//              (wv0,1 = S-waves own 32d; wv2,3 own 96d), S computed transposed,
//              P transposed in registers (cvt_pk + permlane swaps), P shared via
//              fragment-linear LDS (zero conflicts), f/H global->reg ping-pong,
//              RAW s_barrier + lgkmcnt(0) only (no vmcnt drain -> prefetches stay
//              in flight across barriers), exp shift folded into MFMA C-init.
//
// MFMA 16x16x32 lane layouts (verified m89):
//   A[row][k]: row = lane&15, k = (lane>>4)*8 + j
//   B[k][col]: col = lane&15, k = (lane>>4)*8 + j
//   D[row][col]: col = lane&15, row = (lane>>4)*4 + reg

typedef __bf16 bf16x8 __attribute__((ext_vector_type(8)));
typedef float f32x4 __attribute__((ext_vector_type(4)));

#define NPIX 4096
#define CDIM 256
#define CK   32

union U128 { unsigned int d[4]; uint4 u4; bf16x8 v; };

__device__ __forceinline__ unsigned int cvtpk(float lo, float hi) {
    unsigned int r;
    asm("v_cvt_pk_bf16_f32 %0, %1, %2" : "=v"(r) : "v"(lo), "v"(hi));
    return r;
}

// WTf layout: [ct 0..19][kk 0..7][l15 0..15][32]; channel = ct*16+l15, k = kk*32+j.
__global__ __launch_bounds__(256) void prep_wtf(
    const float* __restrict__ Wf, const float* __restrict__ Wg,
    const float* __restrict__ Wh, __bf16* __restrict__ WTf)
{
    const int idx = blockIdx.x * 256 + threadIdx.x;   // 0..81919
    const int j   = idx & 31;
    const int l15 = (idx >> 5) & 15;
    const int kk  = (idx >> 9) & 7;
    const int ct  = idx >> 12;
    const int k   = kk * 32 + j;
    float v;
    if (ct < 2)      v = Wf[k * 32 + ct * 16 + l15];
    else if (ct < 4) v = Wg[k * 32 + (ct - 2) * 16 + l15];
    else             v = Wh[k * 256 + (ct - 4) * 16 + l15];
    WTf[idx] = (__bf16)v;
}

__global__ __launch_bounds__(256, 4) void proj_mfma(
    const float* __restrict__ x, const __bf16* __restrict__ WTf,
    const float* __restrict__ bf_, const float* __restrict__ bg_,
    const float* __restrict__ bh_,
    __bf16* __restrict__ fbuf, __bf16* __restrict__ gbuf,
    __bf16* __restrict__ hT)
{
    // xs: [16 rows][256 k] bf16, 16B-slot XOR swizzle (slot ^= row&7)
    __shared__ __bf16 xs[16 * 256];

    const int t = threadIdx.x;
    const int rowbase = blockIdx.x * 16;   // grid 1024

    {
        const int flat = t * 4;            // one float4 each, plus second half
        #pragma unroll
        for (int i = 0; i < 4; ++i) {
            const int f2 = i * 1024 + flat;
            const int row = f2 >> 8, col = f2 & 255;
            const float4 xv = *(const float4*)&x[(size_t)rowbase * 256 + f2];
            const unsigned int d0 = cvtpk(xv.x, xv.y);
            const unsigned int d1 = cvtpk(xv.z, xv.w);
            const int s = (col >> 3) ^ (row & 7);
            uint2 w; w.x = d0; w.y = d1;
            *(uint2*)&xs[row * 256 + s * 8 + (col & 7)] = w;
        }
    }
    __syncthreads();

    const int wv = t >> 6, lane = t & 63, l15 = lane & 15, lhi = lane >> 4;

    f32x4 acc[5];
    #pragma unroll
    for (int i = 0; i < 5; ++i) acc[i] = (f32x4){0.f, 0.f, 0.f, 0.f};

    #pragma unroll 2
    for (int kk = 0; kk < 8; ++kk) {
        const bf16x8 xfrag =
            *(const bf16x8*)&xs[l15 * 256 + (((kk * 4 + lhi) ^ (l15 & 7)) * 8)];
        #pragma unroll
        for (int j = 0; j < 5; ++j) {
            const int ct = wv + j * 4;
            const bf16x8 w =
                *(const bf16x8*)&WTf[((size_t)(ct * 8 + kk) * 16 + l15) * 32 + lhi * 8];
            if (j == 0)   // fg tile: A=x -> D[pixel][channel]
                acc[j] = __builtin_amdgcn_mfma_f32_16x16x32_bf16(xfrag, w, acc[j], 0, 0, 0);
            else          // h tile: A=w -> D[channel][pixel] (transposed store)
                acc[j] = __builtin_amdgcn_mfma_f32_16x16x32_bf16(w, xfrag, acc[j], 0, 0, 0);
        }
    }

    const int b = rowbase >> 12;
    const int nloc = rowbase & 4095;
    {   // fg tile ct = wv (f: 0,1; g: 2,3)
        const int ct = wv;
        const float bia = (ct < 2) ? bf_[(ct & 1) * 16 + l15] : bg_[(ct & 1) * 16 + l15];
        __bf16* dst = (ct < 2) ? fbuf : gbuf;
        const int ch = (ct & 1) * 16 + l15;
        #pragma unroll
        for (int r = 0; r < 4; ++r)
            dst[(size_t)(rowbase + lhi * 4 + r) * CK + ch] = (__bf16)(acc[0][r] + bia);
    }
    #pragma unroll
    for (int j = 1; j < 5; ++j) {
        const int dtile = wv + (j - 1) * 4;
        #pragma unroll
        for (int r = 0; r < 4; ++r) {
            const int d = dtile * 16 + lhi * 4 + r;
            hT[((size_t)b * CDIM + d) * NPIX + nloc + l15] = (__bf16)(acc[j][r] + bh_[d]);
        }
    }
}

// ---------------- attention ----------------
#define PL32(a, b) asm("v_permlane32_swap_b32 %0, %1" : "+v"(a), "+v"(b))
#define PL16(a, b) asm("v_permlane16_swap_b32 %0, %1" : "+v"(a), "+v"(b))

#define ATTN_TILE(KV, PB, FC, FN, HC, HN)                                           \
do {                                                                                \
    if (wv < 2) {                                                                   \
        const f32x4 m30 = {-30.f, -30.f, -30.f, -30.f};                             \
        f32x4 s0 = __builtin_amdgcn_mfma_f32_16x16x32_bf16(FC[0], ga, m30, 0, 0, 0);\
        f32x4 s1 = __builtin_amdgcn_mfma_f32_16x16x32_bf16(FC[1], ga, m30, 0, 0, 0);\
        f32x4 s2 = __builtin_amdgcn_mfma_f32_16x16x32_bf16(FC[2], ga, m30, 0, 0, 0);\
        f32x4 s3 = __builtin_amdgcn_mfma_f32_16x16x32_bf16(FC[3], ga, m30, 0, 0, 0);\
        {   /* prefetch next f tile (wraps on last: harmless valid read) */         \
            const size_t ko = (size_t)(((KV) + 64) & 4095) * CK;                    \
            FN[0] = *(const bf16x8*)(fp + ko);                                      \
            FN[1] = *(const bf16x8*)(fp + ko + 16 * CK);                            \
            FN[2] = *(const bf16x8*)(fp + ko + 32 * CK);                            \
            FN[3] = *(const bf16x8*)(fp + ko + 48 * CK);                            \
        }                                                                           \
        float p0 = __expf(s0[0]), p1 = __expf(s0[1]), p2 = __expf(s0[2]), p3 = __expf(s0[3]); \
        float p4 = __expf(s1[0]), p5 = __expf(s1[1]), p6 = __expf(s1[2]), p7 = __expf(s1[3]); \
        float p8 = __expf(s2[0]), p9 = __expf(s2[1]), pa_ = __expf(s2[2]), pb_ = __expf(s2[3]); \
        float pc_ = __expf(s3[0]), pd_ = __expf(s3[1]), pe_ = __expf(s3[2]), pf_ = __expf(s3[3]); \
        lsum += ((p0 + p1) + (p2 + p3)) + ((p4 + p5) + (p6 + p7))                   \
              + ((p8 + p9) + (pa_ + pb_)) + ((pc_ + pd_) + (pe_ + pf_));            \
        unsigned int u0 = cvtpk(p0, p1), u1 = cvtpk(p2, p3);                        \
        unsigned int u2 = cvtpk(p4, p5), u3 = cvtpk(p6, p7);                        \
        unsigned int u4 = cvtpk(p8, p9), u5 = cvtpk(pa_, pb_);                      \
        unsigned int u6 = cvtpk(pc_, pd_), u7 = cvtpk(pe_, pf_);                    \
        PL32(u0, u2); PL32(u1, u3); PL32(u4, u6); PL32(u5, u7);                     \
        PL16(u0, u2); PL16(u1, u3); PL16(u4, u6); PL16(u5, u7);                     \
        uint4 w0; w0.x = u0; w0.y = u1; w0.z = u2; w0.w = u3;                       \
        uint4 w1; w1.x = u4; w1.y = u5; w1.z = u6; w1.w = u7;                       \
        pbuf[PB][wv * 2 + 0][lane] = w0;                                            \
        pbuf[PB][wv * 2 + 1][lane] = w1;                                            \
    }                                                                               \
    /* raw barrier: order LDS only; vmem prefetches stay in flight */               \
    asm volatile("s_waitcnt lgkmcnt(0)\n\ts_barrier" ::: "memory");                 \
    {   /* prefetch next H tile */                                                  \
        const size_t kn = (size_t)(((KV) + 64) & 4095);                             \
        HN[0] = *(const bf16x8*)(hp + kn);                                          \
        HN[1] = *(const bf16x8*)(hp + kn + 32);                                     \
        HN[2] = *(const bf16x8*)(hp + (size_t)16 * NPIX + kn);                      \
        HN[3] = *(const bf16x8*)(hp + (size_t)16 * NPIX + kn + 32);                 \
        if (wv >= 2) {                                                              \
            _Pragma("unroll")                                                       \
            for (int dt = 2; dt < 6; ++dt) {                                        \
                HN[dt * 2 + 0] = *(const bf16x8*)(hp + (size_t)dt * 16 * NPIX + kn);\
                HN[dt * 2 + 1] = *(const bf16x8*)(hp + (size_t)dt * 16 * NPIX + kn + 32); \
            }                                                                       \
        }                                                                           \
    }                                                                               \
    __builtin_amdgcn_s_setprio(1);                                                  \
    _Pragma("unroll")                                                               \
    for (int rt = 0; rt < 2; ++rt) {                                                \
        U128 A0, A1;                                                                \
        A0.u4 = pbuf[PB][rt * 2 + 0][lane];                                         \
        A1.u4 = pbuf[PB][rt * 2 + 1][lane];                                         \
        O_[rt][0] = __builtin_amdgcn_mfma_f32_16x16x32_bf16(A0.v, HC[0], O_[rt][0], 0, 0, 0); \
        O_[rt][0] = __builtin_amdgcn_mfma_f32_16x16x32_bf16(A1.v, HC[1], O_[rt][0], 0, 0, 0); \
        O_[rt][1] = __builtin_amdgcn_mfma_f32_16x16x32_bf16(A0.v, HC[2], O_[rt][1], 0, 0, 0); \
        O_[rt][1] = __builtin_amdgcn_mfma_f32_16x16x32_bf16(A1.v, HC[3], O_[rt][1], 0, 0, 0); \
        if (wv >= 2) {                                                              \
            _Pragma("unroll")                                                       \
            for (int dt = 2; dt < 6; ++dt) {                                        \
                O_[rt][dt] = __builtin_amdgcn_mfma_f32_16x16x32_bf16(A0.v, HC[dt * 2 + 0], O_[rt][dt], 0, 0, 0); \
                O_[rt][dt] = __builtin_amdgcn_mfma_f32_16x16x32_bf16(A1.v, HC[dt * 2 + 1], O_[rt][dt], 0, 0, 0); \
            }                                                                       \
        }                                                                           \
    }                                                                               \
    __builtin_amdgcn_s_setprio(0);                                                  \
} while (0)

__global__ __launch_bounds__(256, 2) void attn_kernel(
    const __bf16* __restrict__ fbuf, const __bf16* __restrict__ gbuf,
    const __bf16* __restrict__ hT, const float* __restrict__ x,
    const float* __restrict__ gamma_p, float* __restrict__ out)
{
    __shared__ uint4 pbuf[2][4][64];     // 8 KB, fragment-linear P (zero-conflict)
    __shared__ float lbuf[32];

    const int t = threadIdx.x;
    const int lane = t & 63;
    const int wv = t >> 6;               // 0,1 = S-waves (32d each); 2,3 = 96d each
    const int l15 = lane & 15;
    const int lhi = lane >> 4;

    // XCD swizzle: batch b's 128 blocks -> XCDs {2b,2b+1}; 2 blocks/CU
    const int xcd = blockIdx.x & 7;
    const int b = xcd >> 1;
    const int qt = ((blockIdx.x >> 3) << 1) + (xcd & 1);  // 0..127
    const int q0 = qt * 32;

    const __bf16* fb = fbuf + (size_t)b * NPIX * CK;
    const __bf16* hb = hT + (size_t)b * CDIM * NPIX;

    const int dbase = (wv < 2) ? wv * 32 : 64 + (wv - 2) * 96;
    const __bf16* hp = hb + (size_t)(dbase + l15) * NPIX + lhi * 8;
    const __bf16* fp = fb + (size_t)l15 * CK + lhi * 8;

    bf16x8 ga = {};
    if (wv < 2)
        ga = *(const bf16x8*)&gbuf[((size_t)b * NPIX + q0 + wv * 16 + l15) * CK + lhi * 8];

    f32x4 O_[2][6];
    #pragma unroll
    for (int i = 0; i < 2; ++i)
        #pragma unroll
        for (int j = 0; j < 6; ++j) O_[i][j] = (f32x4){0.f, 0.f, 0.f, 0.f};
    float lsum = 0.f;

    bf16x8 FA[4], FB[4], HA[12], HB[12];

    // prologue: tile 0 operands
    if (wv < 2) {
        FA[0] = *(const bf16x8*)(fp);
        FA[1] = *(const bf16x8*)(fp + 16 * CK);
        FA[2] = *(const bf16x8*)(fp + 32 * CK);
        FA[3] = *(const bf16x8*)(fp + 48 * CK);
    }
    HA[0] = *(const bf16x8*)(hp);
    HA[1] = *(const bf16x8*)(hp + 32);
    HA[2] = *(const bf16x8*)(hp + (size_t)16 * NPIX);
    HA[3] = *(const bf16x8*)(hp + (size_t)16 * NPIX + 32);
    if (wv >= 2) {
        #pragma unroll
        for (int dt = 2; dt < 6; ++dt) {
            HA[dt * 2 + 0] = *(const bf16x8*)(hp + (size_t)dt * 16 * NPIX);
            HA[dt * 2 + 1] = *(const bf16x8*)(hp + (size_t)dt * 16 * NPIX + 32);
        }
    }

    for (int it = 0; it < 32; ++it) {
        const int kv = it * 128;
        ATTN_TILE(kv,      0, FA, FB, HA, HB);
        ATTN_TILE(kv + 64, 1, FB, FA, HB, HA);
    }

    // epilogue
    if (wv < 2) {
        lsum += __shfl_xor(lsum, 16, 64);
        lsum += __shfl_xor(lsum, 32, 64);
        if (lane < 16) lbuf[wv * 16 + l15] = lsum;
    }
    __syncthreads();

    const float gm = gamma_p[0];
    #pragma unroll
    for (int rt = 0; rt < 2; ++rt) {
        #pragma unroll
        for (int r = 0; r < 4; ++r) {
            const int row = rt * 16 + lhi * 4 + r;
            const float rl = gm / lbuf[row];
            const size_t base = ((size_t)b * NPIX + q0 + row) * CDIM + dbase;
            out[base + l15]      = fmaf(rl, O_[rt][0][r], x[base + l15]);
            out[base + 16 + l15] = fmaf(rl, O_[rt][1][r], x[base + 16 + l15]);
            if (wv >= 2) {
                #pragma unroll
                for (int dt = 2; dt < 6; ++dt)
                    out[base + dt * 16 + l15] =
                        fmaf(rl, O_[rt][dt][r], x[base + dt * 16 + l15]);
            }
        }
    }
}

extern "C" void kernel_launch(void* const* d_in, const int* in_sizes, int n_in,
                              void* d_out, int out_size, void* d_ws, size_t ws_size,
                              hipStream_t stream)
{
    const float* x     = (const float*)d_in[0];
    const float* Wf    = (const float*)d_in[1];
    const float* bf    = (const float*)d_in[2];
    const float* Wg    = (const float*)d_in[3];
    const float* bg    = (const float*)d_in[4];
    const float* Wh    = (const float*)d_in[5];
    const float* bh    = (const float*)d_in[6];
    const float* gamma = (const float*)d_in[7];
    float* out = (float*)d_out;

    // workspace: f (1MB) | g (1MB) | hT (8MB) | WTf (160KB), all bf16
    __bf16* fbuf = (__bf16*)d_ws;
    __bf16* gbuf = fbuf + (size_t)4 * NPIX * CK;
    __bf16* hT   = gbuf + (size_t)4 * NPIX * CK;
    __bf16* WTf  = hT + (size_t)4 * CDIM * NPIX;

    prep_wtf<<<320, 256, 0, stream>>>(Wf, Wg, Wh, WTf);
    proj_mfma<<<1024, 256, 0, stream>>>(x, WTf, bf, bg, bh, fbuf, gbuf, hT);
    attn_kernel<<<512, 256, 0, stream>>>(fbuf, gbuf, hT, x, gamma, out);
}

// Round 9
// 226.968 us; speedup vs baseline: 1.0382x; 1.0382x over previous
//
#include <hip/hip_runtime.h>
#include <hip/hip_bf16.h>
#include <math.h>

// SAGAN self-attention, B=4, H=W=64, C=256, Ck=32, N=4096 (16384 total rows).
//   prep_wtf : WTf fragment-contiguous repack of [Wf|Wg|Wh]^T (bf16).
//   proj_mfma: 16-row blocks, grid 1024, 4 symmetric waves -> f,g bf16 [B*N,32],
//              hT bf16 [B,256,4096] (transposed via swapped-operand MFMA).
//   attn     : flash attention, Q-tile 64, grid 256, 512 threads, 8 waves:
//              wv0-3 compute S (q-block wv) then PV a 16-d slice; wv4-7 PV 48-d slices.
//              S computed transposed, P transposed in registers (cvt_pk + permlane),
//              P shared via fragment-linear LDS (zero conflicts), f/H L2->reg
//              ping-pong prefetch. ONE change vs the round-5 97us kernel:
//              per-tile barrier is lgkmcnt-only (s_waitcnt lgkmcnt(0); s_barrier)
//              so vmem prefetches stay in flight across tile boundaries.
//
// MFMA 16x16x32 lane layouts (verified m89):
//   A[row][k]: row = lane&15, k = (lane>>4)*8 + j
//   B[k][col]: col = lane&15, k = (lane>>4)*8 + j
//   D[row][col]: col = lane&15, row = (lane>>4)*4 + reg

typedef __bf16 bf16x8 __attribute__((ext_vector_type(8)));
typedef float f32x4 __attribute__((ext_vector_type(4)));

#define NPIX 4096
#define CDIM 256
#define CK   32

union U128 { unsigned int d[4]; uint4 u4; bf16x8 v; };

__device__ __forceinline__ unsigned int cvtpk(float lo, float hi) {
    unsigned int r;
    asm("v_cvt_pk_bf16_f32 %0, %1, %2" : "=v"(r) : "v"(lo), "v"(hi));
    return r;
}

// WTf layout: [ct 0..19][kk 0..7][l15 0..15][32]; channel = ct*16+l15, k = kk*32+j.
__global__ __launch_bounds__(256) void prep_wtf(
    const float* __restrict__ Wf, const float* __restrict__ Wg,
    const float* __restrict__ Wh, __bf16* __restrict__ WTf)
{
    const int idx = blockIdx.x * 256 + threadIdx.x;   // 0..81919
    const int j   = idx & 31;
    const int l15 = (idx >> 5) & 15;
    const int kk  = (idx >> 9) & 7;
    const int ct  = idx >> 12;
    const int k   = kk * 32 + j;
    float v;
    if (ct < 2)      v = Wf[k * 32 + ct * 16 + l15];
    else if (ct < 4) v = Wg[k * 32 + (ct - 2) * 16 + l15];
    else             v = Wh[k * 256 + (ct - 4) * 16 + l15];
    WTf[idx] = (__bf16)v;
}

__global__ __launch_bounds__(256, 4) void proj_mfma(
    const float* __restrict__ x, const __bf16* __restrict__ WTf,
    const float* __restrict__ bf_, const float* __restrict__ bg_,
    const float* __restrict__ bh_,
    __bf16* __restrict__ fbuf, __bf16* __restrict__ gbuf,
    __bf16* __restrict__ hT)
{
    // xs: [16 rows][256 k] bf16, 16B-slot XOR swizzle (slot ^= row&7)
    __shared__ __bf16 xs[16 * 256];

    const int t = threadIdx.x;
    const int rowbase = blockIdx.x * 16;   // grid 1024

    {
        const int flat = t * 4;
        #pragma unroll
        for (int i = 0; i < 4; ++i) {
            const int f2 = i * 1024 + flat;
            const int row = f2 >> 8, col = f2 & 255;
            const float4 xv = *(const float4*)&x[(size_t)rowbase * 256 + f2];
            const unsigned int d0 = cvtpk(xv.x, xv.y);
            const unsigned int d1 = cvtpk(xv.z, xv.w);
            const int s = (col >> 3) ^ (row & 7);
            uint2 w; w.x = d0; w.y = d1;
            *(uint2*)&xs[row * 256 + s * 8 + (col & 7)] = w;
        }
    }
    __syncthreads();

    const int wv = t >> 6, lane = t & 63, l15 = lane & 15, lhi = lane >> 4;

    f32x4 acc[5];
    #pragma unroll
    for (int i = 0; i < 5; ++i) acc[i] = (f32x4){0.f, 0.f, 0.f, 0.f};

    #pragma unroll 2
    for (int kk = 0; kk < 8; ++kk) {
        const bf16x8 xfrag =
            *(const bf16x8*)&xs[l15 * 256 + (((kk * 4 + lhi) ^ (l15 & 7)) * 8)];
        #pragma unroll
        for (int j = 0; j < 5; ++j) {
            const int ct = wv + j * 4;
            const bf16x8 w =
                *(const bf16x8*)&WTf[((size_t)(ct * 8 + kk) * 16 + l15) * 32 + lhi * 8];
            if (j == 0)   // fg tile: A=x -> D[pixel][channel]
                acc[j] = __builtin_amdgcn_mfma_f32_16x16x32_bf16(xfrag, w, acc[j], 0, 0, 0);
            else          // h tile: A=w -> D[channel][pixel] (transposed store)
                acc[j] = __builtin_amdgcn_mfma_f32_16x16x32_bf16(w, xfrag, acc[j], 0, 0, 0);
        }
    }

    const int b = rowbase >> 12;
    const int nloc = rowbase & 4095;
    {   // fg tile ct = wv (f: 0,1; g: 2,3)
        const int ct = wv;
        const float bia = (ct < 2) ? bf_[(ct & 1) * 16 + l15] : bg_[(ct & 1) * 16 + l15];
        __bf16* dst = (ct < 2) ? fbuf : gbuf;
        const int ch = (ct & 1) * 16 + l15;
        #pragma unroll
        for (int r = 0; r < 4; ++r)
            dst[(size_t)(rowbase + lhi * 4 + r) * CK + ch] = (__bf16)(acc[0][r] + bia);
    }
    #pragma unroll
    for (int j = 1; j < 5; ++j) {
        const int dtile = wv + (j - 1) * 4;
        #pragma unroll
        for (int r = 0; r < 4; ++r) {
            const int d = dtile * 16 + lhi * 4 + r;
            hT[((size_t)b * CDIM + d) * NPIX + nloc + l15] = (__bf16)(acc[j][r] + bh_[d]);
        }
    }
}

// ---------------- attention ----------------
#define PL32(a, b) asm("v_permlane32_swap_b32 %0, %1" : "+v"(a), "+v"(b))
#define PL16(a, b) asm("v_permlane16_swap_b32 %0, %1" : "+v"(a), "+v"(b))
// lgkmcnt-only barrier: orders LDS, leaves vmem prefetches in flight.
#define RAW_BAR asm volatile("s_waitcnt lgkmcnt(0)\n\ts_barrier" ::: "memory")

#define ATTN_TILE(KV, PB, FC, FN, HC, HN)                                           \
do {                                                                                \
    if (wv < 4) {                                                                   \
        const f32x4 m30 = {-30.f, -30.f, -30.f, -30.f};                             \
        f32x4 s0 = __builtin_amdgcn_mfma_f32_16x16x32_bf16(FC[0], ga, m30, 0, 0, 0);\
        f32x4 s1 = __builtin_amdgcn_mfma_f32_16x16x32_bf16(FC[1], ga, m30, 0, 0, 0);\
        f32x4 s2 = __builtin_amdgcn_mfma_f32_16x16x32_bf16(FC[2], ga, m30, 0, 0, 0);\
        f32x4 s3 = __builtin_amdgcn_mfma_f32_16x16x32_bf16(FC[3], ga, m30, 0, 0, 0);\
        {   /* prefetch next f tile (wrap: harmless valid read) */                  \
            const size_t ko = (size_t)(((KV) + 64) & 4095) * CK;                    \
            FN[0] = *(const bf16x8*)(fp + ko);                                      \
            FN[1] = *(const bf16x8*)(fp + ko + 16 * CK);                            \
            FN[2] = *(const bf16x8*)(fp + ko + 32 * CK);                            \
            FN[3] = *(const bf16x8*)(fp + ko + 48 * CK);                            \
        }                                                                           \
        float p0 = __expf(s0[0]), p1 = __expf(s0[1]), p2 = __expf(s0[2]), p3 = __expf(s0[3]); \
        float p4 = __expf(s1[0]), p5 = __expf(s1[1]), p6 = __expf(s1[2]), p7 = __expf(s1[3]); \
        float p8 = __expf(s2[0]), p9 = __expf(s2[1]), pa_ = __expf(s2[2]), pb_ = __expf(s2[3]); \
        float pc_ = __expf(s3[0]), pd_ = __expf(s3[1]), pe_ = __expf(s3[2]), pf_ = __expf(s3[3]); \
        lsum += ((p0 + p1) + (p2 + p3)) + ((p4 + p5) + (p6 + p7))                   \
              + ((p8 + p9) + (pa_ + pb_)) + ((pc_ + pd_) + (pe_ + pf_));            \
        unsigned int u0 = cvtpk(p0, p1), u1 = cvtpk(p2, p3);                        \
        unsigned int u2 = cvtpk(p4, p5), u3 = cvtpk(p6, p7);                        \
        unsigned int u4 = cvtpk(p8, p9), u5 = cvtpk(pa_, pb_);                      \
        unsigned int u6 = cvtpk(pc_, pd_), u7 = cvtpk(pe_, pf_);                    \
        PL32(u0, u2); PL32(u1, u3); PL32(u4, u6); PL32(u5, u7);                     \
        PL16(u0, u2); PL16(u1, u3); PL16(u4, u6); PL16(u5, u7);                     \
        uint4 w0; w0.x = u0; w0.y = u1; w0.z = u2; w0.w = u3;                       \
        uint4 w1; w1.x = u4; w1.y = u5; w1.z = u6; w1.w = u7;                       \
        pbuf[PB][wv * 2 + 0][lane] = w0;                                            \
        pbuf[PB][wv * 2 + 1][lane] = w1;                                            \
    }                                                                               \
    RAW_BAR;                                                                        \
    {   /* prefetch next H tile */                                                  \
        const size_t kn = (size_t)(((KV) + 64) & 4095);                             \
        HN[0] = *(const bf16x8*)(hp + kn);                                          \
        HN[1] = *(const bf16x8*)(hp + kn + 32);                                     \
        if (wv >= 4) {                                                              \
            _Pragma("unroll")                                                       \
            for (int dt = 1; dt < 3; ++dt) {                                        \
                HN[dt * 2 + 0] = *(const bf16x8*)(hp + (size_t)dt * 16 * NPIX + kn);\
                HN[dt * 2 + 1] = *(const bf16x8*)(hp + (size_t)dt * 16 * NPIX + kn + 32); \
            }                                                                       \
        }                                                                           \
    }                                                                               \
    __builtin_amdgcn_s_setprio(1);                                                  \
    _Pragma("unroll")                                                               \
    for (int rt = 0; rt < 4; ++rt) {                                                \
        U128 A0, A1;                                                                \
        A0.u4 = pbuf[PB][rt * 2 + 0][lane];                                         \
        A1.u4 = pbuf[PB][rt * 2 + 1][lane];                                         \
        O_[rt][0] = __builtin_amdgcn_mfma_f32_16x16x32_bf16(A0.v, HC[0], O_[rt][0], 0, 0, 0); \
        O_[rt][0] = __builtin_amdgcn_mfma_f32_16x16x32_bf16(A1.v, HC[1], O_[rt][0], 0, 0, 0); \
        if (wv >= 4) {                                                              \
            _Pragma("unroll")                                                       \
            for (int dt = 1; dt < 3; ++dt) {                                        \
                O_[rt][dt] = __builtin_amdgcn_mfma_f32_16x16x32_bf16(A0.v, HC[dt * 2 + 0], O_[rt][dt], 0, 0, 0); \
                O_[rt][dt] = __builtin_amdgcn_mfma_f32_16x16x32_bf16(A1.v, HC[dt * 2 + 1], O_[rt][dt], 0, 0, 0); \
            }                                                                       \
        }                                                                           \
    }                                                                               \
    __builtin_amdgcn_s_setprio(0);                                                  \
} while (0)

__global__ __launch_bounds__(512, 1) void attn_kernel(
    const __bf16* __restrict__ fbuf, const __bf16* __restrict__ gbuf,
    const __bf16* __restrict__ hT, const float* __restrict__ x,
    const float* __restrict__ gamma_p, float* __restrict__ out)
{
    __shared__ uint4 pbuf[2][8][64];     // 16 KB, fragment-linear P (zero-conflict)
    __shared__ float lbuf[64];

    const int t = threadIdx.x;
    const int lane = t & 63;
    const int wv = t >> 6;               // 0-3: S-waves + 16d PV; 4-7: 48d PV
    const int l15 = lane & 15;
    const int lhi = lane >> 4;

    // XCD swizzle: batch b's 64 blocks -> XCDs {2b,2b+1}; hT batch (2MB) L2-fits.
    const int xcd = blockIdx.x & 7;
    const int b = xcd >> 1;
    const int qt = ((blockIdx.x >> 3) << 1) + (xcd & 1);  // 0..63
    const int q0 = qt * 64;

    const __bf16* fb = fbuf + (size_t)b * NPIX * CK;
    const __bf16* hb = hT + (size_t)b * CDIM * NPIX;

    // uneven d-split: S-waves own 16 d, big waves own 48 d
    const int dbase = (wv < 4) ? wv * 16 : 64 + (wv - 4) * 48;
    const __bf16* hp = hb + (size_t)(dbase + l15) * NPIX + lhi * 8;
    const __bf16* fp = fb + (size_t)l15 * CK + lhi * 8;   // + kv*CK + cb*16*CK

    bf16x8 ga = {};
    if (wv < 4)
        ga = *(const bf16x8*)&gbuf[((size_t)b * NPIX + q0 + wv * 16 + l15) * CK + lhi * 8];

    f32x4 O_[4][3];
    #pragma unroll
    for (int i = 0; i < 4; ++i)
        #pragma unroll
        for (int j = 0; j < 3; ++j) O_[i][j] = (f32x4){0.f, 0.f, 0.f, 0.f};
    float lsum = 0.f;

    bf16x8 FA[4], FB[4], HA[6], HB[6];

    // prologue: tile 0 operands
    if (wv < 4) {
        FA[0] = *(const bf16x8*)(fp);
        FA[1] = *(const bf16x8*)(fp + 16 * CK);
        FA[2] = *(const bf16x8*)(fp + 32 * CK);
        FA[3] = *(const bf16x8*)(fp + 48 * CK);
    }
    HA[0] = *(const bf16x8*)(hp);
    HA[1] = *(const bf16x8*)(hp + 32);
    if (wv >= 4) {
        #pragma unroll
        for (int dt = 1; dt < 3; ++dt) {
            HA[dt * 2 + 0] = *(const bf16x8*)(hp + (size_t)dt * 16 * NPIX);
            HA[dt * 2 + 1] = *(const bf16x8*)(hp + (size_t)dt * 16 * NPIX + 32);
        }
    }

    for (int it = 0; it < 32; ++it) {
        const int kv = it * 128;
        ATTN_TILE(kv,      0, FA, FB, HA, HB);
        ATTN_TILE(kv + 64, 1, FB, FA, HB, HA);
    }

    // epilogue: lsum reduce (per q = l15 within S-wave), share, write out
    if (wv < 4) {
        lsum += __shfl_xor(lsum, 16, 64);
        lsum += __shfl_xor(lsum, 32, 64);
        if (lane < 16) lbuf[wv * 16 + l15] = lsum;
    }
    __syncthreads();

    const float gm = gamma_p[0];
    #pragma unroll
    for (int rt = 0; rt < 4; ++rt) {
        #pragma unroll
        for (int r = 0; r < 4; ++r) {
            const int row = rt * 16 + lhi * 4 + r;
            const float rl = gm / lbuf[row];
            const size_t base = ((size_t)b * NPIX + q0 + row) * CDIM + dbase;
            out[base + l15] = fmaf(rl, O_[rt][0][r], x[base + l15]);
            if (wv >= 4) {
                #pragma unroll
                for (int dt = 1; dt < 3; ++dt)
                    out[base + dt * 16 + l15] =
                        fmaf(rl, O_[rt][dt][r], x[base + dt * 16 + l15]);
            }
        }
    }
}

extern "C" void kernel_launch(void* const* d_in, const int* in_sizes, int n_in,
                              void* d_out, int out_size, void* d_ws, size_t ws_size,
                              hipStream_t stream)
{
    const float* x     = (const float*)d_in[0];
    const float* Wf    = (const float*)d_in[1];
    const float* bf    = (const float*)d_in[2];
    const float* Wg    = (const float*)d_in[3];
    const float* bg    = (const float*)d_in[4];
    const float* Wh    = (const float*)d_in[5];
    const float* bh    = (const float*)d_in[6];
    const float* gamma = (const float*)d_in[7];
    float* out = (float*)d_out;

    // workspace: f (1MB) | g (1MB) | hT (8MB) | WTf (160KB), all bf16
    __bf16* fbuf = (__bf16*)d_ws;
    __bf16* gbuf = fbuf + (size_t)4 * NPIX * CK;
    __bf16* hT   = gbuf + (size_t)4 * NPIX * CK;
    __bf16* WTf  = hT + (size_t)4 * CDIM * NPIX;

    prep_wtf<<<320, 256, 0, stream>>>(Wf, Wg, Wh, WTf);
    proj_mfma<<<1024, 256, 0, stream>>>(x, WTf, bf, bg, bh, fbuf, gbuf, hT);
    attn_kernel<<<256, 512, 0, stream>>>(fbuf, gbuf, hT, x, gamma, out);
}